// Round 1
// baseline (597.133 us; speedup 1.0000x reference)
//
#include <hip/hip_runtime.h>
#include <hip/hip_bf16.h>

// Grouped GEMM: E=16 experts, each [2048x1024] @ [1024x4096], fp32 in/out.
// Strategy: bf16 MFMA (16x16x32) with fp32 accumulate; fused fp32->bf16
// conversion during LDS staging; W tile transposed into LDS ([N][K]) so both
// operands read K-contiguous ds_read_b128 fragments.

#define E_NUM 16
#define M_PER_E 2048
#define K_DIM 1024
#define N_DIM 4096
#define BM 128
#define BN 128
#define BK 64
#define KT (K_DIM / BK)   // 16 K-steps

typedef float  float4v  __attribute__((ext_vector_type(4)));
typedef float  f32x4    __attribute__((ext_vector_type(4)));
typedef short  bf16x8   __attribute__((ext_vector_type(8)));
typedef unsigned short ushort4v __attribute__((ext_vector_type(4)));

// XOR swizzle on the 16B-slot index within a 128B LDS row.
// Chosen so stride-1-row reads AND stride-4-row writes both hit >=8 distinct
// 16B slots (2-way max aliasing = free per m136).
__device__ __forceinline__ int swz(int row, int kelem) {
    return kelem ^ (((row ^ (row >> 3)) & 7) << 3);
}

__device__ __forceinline__ ushort4v cvt4_bf16(float4v f) {
    union { __bf16 h[4]; ushort4v u; } x;
#pragma unroll
    for (int j = 0; j < 4; ++j) x.h[j] = (__bf16)f[j];
    return x.u;
}

__global__ __launch_bounds__(256) void grouped_gemm_kernel(
    const float* __restrict__ A,   // [E*2048, 1024]
    const float* __restrict__ W,   // [E, 1024, 4096]
    float* __restrict__ C)         // [E*2048, 4096]
{
    const int bn = blockIdx.x;     // N tile: 0..31
    const int bm = blockIdx.y;     // M tile: 0..15
    const int e  = blockIdx.z;     // expert: 0..15
    const int tid  = threadIdx.x;
    const int lane = tid & 63;
    const int wid  = tid >> 6;
    const int wr   = wid >> 1;     // wave row 0..1  (64 rows each)
    const int wc   = wid & 1;      // wave col 0..1  (64 cols each)

    __shared__ __align__(16) unsigned short sA[BM * BK];  // [m][k] bf16, swizzled
    __shared__ __align__(16) unsigned short sB[BN * BK];  // [n][k] bf16 (W transposed), swizzled

    const float* Abase = A + ((size_t)e * M_PER_E + (size_t)bm * BM) * K_DIM;
    const float* Wbase = W + (size_t)e * K_DIM * N_DIM + (size_t)bn * BN;
    float*       Cbase = C + ((size_t)e * M_PER_E + (size_t)bm * BM) * N_DIM + (size_t)bn * BN;

    // staging maps
    const int arow  = tid >> 4;        // 0..15 (A row within 16-row group)
    const int acol4 = (tid & 15) * 4;  // 0..60 (A k quad)
    const int bkq   = tid >> 4;        // 0..15 (B k-quad)
    const int bnq   = tid & 15;        // 0..15 (B n-quad)

    f32x4 acc[4][4];
#pragma unroll
    for (int m = 0; m < 4; ++m)
#pragma unroll
        for (int n = 0; n < 4; ++n) acc[m][n] = (f32x4)0.0f;

    float4v ra[8], rb[8];

    // issue the 16 global float4 loads for K-tile kt
    auto LOADT = [&](int kt) {
        const float* ap = Abase + (size_t)arow * K_DIM + kt * BK + acol4;
#pragma unroll
        for (int i = 0; i < 8; ++i)
            ra[i] = *reinterpret_cast<const float4v*>(ap + (size_t)i * 16 * K_DIM);
        const float* bp = Wbase + (size_t)(kt * BK + bkq * 4) * N_DIM + bnq * 4;
#pragma unroll
        for (int i = 0; i < 2; ++i)
#pragma unroll
            for (int r = 0; r < 4; ++r)
                rb[i * 4 + r] = *reinterpret_cast<const float4v*>(bp + (size_t)r * N_DIM + i * 64);
    };

    // convert staged regs to bf16 and write LDS (A direct, B transposed)
    auto STORET = [&]() {
#pragma unroll
        for (int i = 0; i < 8; ++i) {
            int row = arow + i * 16;
            ushort4v v = cvt4_bf16(ra[i]);
            *reinterpret_cast<ushort4v*>(&sA[row * BK + swz(row, acol4)]) = v;
        }
#pragma unroll
        for (int i = 0; i < 2; ++i) {
#pragma unroll
            for (int j = 0; j < 4; ++j) {
                int n = (bnq + i * 16) * 4 + j;
                float4v col;
                col[0] = rb[i * 4 + 0][j];
                col[1] = rb[i * 4 + 1][j];
                col[2] = rb[i * 4 + 2][j];
                col[3] = rb[i * 4 + 3][j];
                ushort4v v = cvt4_bf16(col);
                *reinterpret_cast<ushort4v*>(&sB[n * BK + swz(n, bkq * 4)]) = v;
            }
        }
    };

    auto COMPUTE = [&]() {
#pragma unroll
        for (int s = 0; s < 2; ++s) {   // two k=32 slices of BK=64
            bf16x8 af[4], bfr[4];
            const int ke = s * 32 + (lane >> 4) * 8;
#pragma unroll
            for (int m = 0; m < 4; ++m) {
                int row = wr * 64 + m * 16 + (lane & 15);
                af[m] = *reinterpret_cast<const bf16x8*>(&sA[row * BK + swz(row, ke)]);
            }
#pragma unroll
            for (int n = 0; n < 4; ++n) {
                int row = wc * 64 + n * 16 + (lane & 15);
                bfr[n] = *reinterpret_cast<const bf16x8*>(&sB[row * BK + swz(row, ke)]);
            }
#pragma unroll
            for (int m = 0; m < 4; ++m)
#pragma unroll
                for (int n = 0; n < 4; ++n)
                    acc[m][n] = __builtin_amdgcn_mfma_f32_16x16x32_bf16(
                        af[m], bfr[n], acc[m][n], 0, 0, 0);
        }
    };

    // prologue
    LOADT(0);
    STORET();
    __syncthreads();

    for (int kt = 0; kt < KT; ++kt) {
        if (kt + 1 < KT) LOADT(kt + 1);   // async: in flight under MFMA
        COMPUTE();
        __syncthreads();                  // all LDS reads done
        if (kt + 1 < KT) STORET();        // vmcnt wait happens here
        __syncthreads();
    }

    // epilogue: C/D layout col=lane&15, row=(lane>>4)*4+j  [m89]
#pragma unroll
    for (int m = 0; m < 4; ++m) {
#pragma unroll
        for (int n = 0; n < 4; ++n) {
#pragma unroll
            for (int j = 0; j < 4; ++j) {
                int row = wr * 64 + m * 16 + (lane >> 4) * 4 + j;
                int col = wc * 64 + n * 16 + (lane & 15);
                Cbase[(size_t)row * N_DIM + col] = acc[m][n][j];
            }
        }
    }
}

extern "C" void kernel_launch(void* const* d_in, const int* in_sizes, int n_in,
                              void* d_out, int out_size, void* d_ws, size_t ws_size,
                              hipStream_t stream) {
    const float* A = (const float*)d_in[0];
    // d_in[1] = expert_size (static 2048 each) — unused
    const float* W = (const float*)d_in[2];
    float* out = (float*)d_out;

    dim3 grid(N_DIM / BN, M_PER_E / BM, E_NUM);  // 32 x 16 x 16
    dim3 block(256);
    hipLaunchKernelGGL(grouped_gemm_kernel, grid, block, 0, stream, A, W, out);
}

// Round 2
// 582.368 us; speedup vs baseline: 1.0254x; 1.0254x over previous
//
#include <hip/hip_runtime.h>
#include <hip/hip_bf16.h>

// Grouped GEMM: E=16 experts, each [2048x1024] @ [1024x4096], fp32 in/out.
// Round 2 strategy:
//   Pass 1a: convert A fp32 -> bf16 into d_ws            (coalesced, vectorized)
//   Pass 1b: transpose+convert W [K][N] fp32 -> WT [N][K] bf16 (LDS tile, XOR-swz)
//   Pass 2 : m97-structure bf16 GEMM: 128x128 tile, BK=32, global_load_lds w=16,
//            linear LDS dest + inverse-swizzled global src + swizzled ds_read_b128,
//            double-buffered LDS, 1 barrier/K-step, XCD-bijective block swizzle.
// Fallback: if ws_size too small, run the round-1 fused kernel.

#define E_NUM 16
#define M_PER_E 2048
#define K_DIM 1024
#define N_DIM 4096

#define A_ELEMS (E_NUM * M_PER_E * K_DIM)   // 33,554,432
#define W_ELEMS (E_NUM * K_DIM * N_DIM)     // 67,108,864
#define WS_NEEDED ((size_t)A_ELEMS * 2 + (size_t)W_ELEMS * 2)  // 201,326,592 B

typedef float  float4v  __attribute__((ext_vector_type(4)));
typedef float  f32x4    __attribute__((ext_vector_type(4)));
typedef short  bf16x8   __attribute__((ext_vector_type(8)));
typedef unsigned short ushort4v __attribute__((ext_vector_type(4)));
typedef unsigned short ushort8v __attribute__((ext_vector_type(8)));

__device__ __forceinline__ ushort4v cvt4_bf16(float4v f) {
    union { __bf16 h[4]; ushort4v u; } x;
#pragma unroll
    for (int j = 0; j < 4; ++j) x.h[j] = (__bf16)f[j];
    return x.u;
}

// ---------------- Pass 1a: A fp32 -> bf16 ----------------
__global__ __launch_bounds__(256) void convertA_kernel(
    const float* __restrict__ A, unsigned short* __restrict__ out, int n8)
{
    int idx = blockIdx.x * 256 + threadIdx.x;
    int stride = gridDim.x * 256;
    for (int i = idx; i < n8; i += stride) {
        float4v a = *reinterpret_cast<const float4v*>(A + (size_t)i * 8);
        float4v b = *reinterpret_cast<const float4v*>(A + (size_t)i * 8 + 4);
        ushort8v v;
        ushort4v va = cvt4_bf16(a), vb = cvt4_bf16(b);
#pragma unroll
        for (int j = 0; j < 4; ++j) { v[j] = va[j]; v[j + 4] = vb[j]; }
        *reinterpret_cast<ushort8v*>(out + (size_t)i * 8) = v;
    }
}

// ---------------- Pass 1b: W [E][K][N] fp32 -> WT [E][N][K] bf16 ----------------
// 64x64 tile per block. LDS float T[64][64] with float4-slot XOR swizzle:
// data (k, n4-slot s) stored at slot s ^ ((k>>3)&7)  -> both write (2-way) and
// read (conflict-free) phases are bank-clean.
__global__ __launch_bounds__(256) void transposeW_kernel(
    const float* __restrict__ W, unsigned short* __restrict__ WT)
{
    const int nt = blockIdx.x;   // 0..63  (N tiles)
    const int kt = blockIdx.y;   // 0..15  (K tiles)
    const int e  = blockIdx.z;   // 0..15
    const int t  = threadIdx.x;

    __shared__ __align__(16) float T[64 * 64];

    const float* Wb = W + ((size_t)e * K_DIM + (size_t)kt * 64) * N_DIM + nt * 64;

#pragma unroll
    for (int j = 0; j < 4; ++j) {
        int kl = (t >> 4) + j * 16;
        int n4 = t & 15;
        float4v v = *reinterpret_cast<const float4v*>(Wb + (size_t)kl * N_DIM + n4 * 4);
        int sp = n4 ^ ((kl >> 3) & 7);
        *reinterpret_cast<float4v*>(&T[kl * 64 + sp * 4]) = v;
    }
    __syncthreads();

#pragma unroll
    for (int c = 0; c < 2; ++c) {
        int nl = (t >> 3) + c * 32;
        int kc = t & 7;
        ushort8v v;
#pragma unroll
        for (int j = 0; j < 8; ++j) {
            int kl = kc * 8 + j;
            int sp = (nl >> 2) ^ kc;           // (kl>>3)&7 == kc here
            float f = T[kl * 64 + sp * 4 + (nl & 3)];
            v[j] = (unsigned short)__builtin_bit_cast(unsigned int,
                       (float)0) ; // placeholder overwritten below
            union { __bf16 h; unsigned short u; } cv; cv.h = (__bf16)f;
            v[j] = cv.u;
        }
        unsigned short* dst = WT + ((size_t)e * N_DIM + (size_t)nt * 64 + nl) * K_DIM
                              + (size_t)kt * 64 + kc * 8;
        *reinterpret_cast<ushort8v*>(dst) = v;
    }
}

// ---------------- Pass 2: bf16 GEMM (m97 structure) ----------------
#define GBM 128
#define GBN 128
#define GBK 32
#define GKT (K_DIM / GBK)   // 32

__global__ __launch_bounds__(256) void gemm_bf16_kernel(
    const unsigned short* __restrict__ A,   // [E*2048][1024] bf16
    const unsigned short* __restrict__ B,   // [E*4096][1024] bf16 (W^T)
    float* __restrict__ C)                  // [E*2048][4096] fp32
{
    // XCD-bijective swizzle over 8192 blocks (8192 % 8 == 0)
    const int bid = blockIdx.x;
    const int swzid = (bid & 7) * (8192 / 8) + (bid >> 3);
    const int e  = swzid >> 9;          // /512
    const int rem = swzid & 511;
    const int bm = rem >> 5;            // /32  -> 0..15
    const int bn = rem & 31;            // 0..31

    const int tid  = threadIdx.x;
    const int lane = tid & 63;
    const int wid  = tid >> 6;
    const int wr   = wid >> 1;
    const int wc   = wid & 1;

    __shared__ __align__(16) unsigned short sA[2][GBM * GBK];  // 8 KB each
    __shared__ __align__(16) unsigned short sB[2][GBN * GBK];  // 8 KB each

    const unsigned short* Abase = A + ((size_t)e * M_PER_E + (size_t)bm * GBM) * K_DIM;
    const unsigned short* Bbase = B + ((size_t)e * N_DIM  + (size_t)bn * GBN) * K_DIM;
    float*                Cbase = C + ((size_t)e * M_PER_E + (size_t)bm * GBM) * N_DIM
                                    + (size_t)bn * GBN;

    // staging geometry: one gload_lds = 64 lanes x 16B = 1KB = 16 rows of 64B.
    // lane l -> row (l>>2), phys slot (l&3). inverse swizzle on global chunk:
    // c = (l&3) ^ ((l>>2)&3)
    const int srow = lane >> 2;
    const int schunk = (lane & 3) ^ ((lane >> 2) & 3);

    auto STAGE = [&](int buf, int kt) {
#pragma unroll
        for (int i = 0; i < 2; ++i) {
            int rbase = (wid * 2 + i) * 16;
            const unsigned short* ga = Abase + (size_t)(rbase + srow) * K_DIM
                                       + kt * GBK + schunk * 8;
            __builtin_amdgcn_global_load_lds(
                (const __attribute__((address_space(1))) void*)ga,
                (__attribute__((address_space(3))) void*)&sA[buf][rbase * GBK],
                16, 0, 0);
            const unsigned short* gb = Bbase + (size_t)(rbase + srow) * K_DIM
                                       + kt * GBK + schunk * 8;
            __builtin_amdgcn_global_load_lds(
                (const __attribute__((address_space(1))) void*)gb,
                (__attribute__((address_space(3))) void*)&sB[buf][rbase * GBK],
                16, 0, 0);
        }
    };

    f32x4 acc[4][4];
#pragma unroll
    for (int m = 0; m < 4; ++m)
#pragma unroll
        for (int n = 0; n < 4; ++n) acc[m][n] = (f32x4)0.0f;

    const int kq = lane >> 4;   // logical k-chunk 0..3

    auto COMPUTE = [&](int buf) {
        bf16x8 af[4], bfr[4];
#pragma unroll
        for (int m = 0; m < 4; ++m) {
            int row = wr * 64 + m * 16 + (lane & 15);
            int ps = kq ^ (row & 3);
            af[m] = *reinterpret_cast<const bf16x8*>(&sA[buf][row * GBK + ps * 8]);
        }
#pragma unroll
        for (int n = 0; n < 4; ++n) {
            int row = wc * 64 + n * 16 + (lane & 15);
            int ps = kq ^ (row & 3);
            bfr[n] = *reinterpret_cast<const bf16x8*>(&sB[buf][row * GBK + ps * 8]);
        }
#pragma unroll
        for (int m = 0; m < 4; ++m)
#pragma unroll
            for (int n = 0; n < 4; ++n)
                acc[m][n] = __builtin_amdgcn_mfma_f32_16x16x32_bf16(
                    af[m], bfr[n], acc[m][n], 0, 0, 0);
    };

    STAGE(0, 0);
    __syncthreads();
    int buf = 0;
#pragma unroll 1
    for (int kt = 0; kt < GKT - 1; ++kt) {
        STAGE(buf ^ 1, kt + 1);   // loads stay in flight under MFMA
        COMPUTE(buf);
        __syncthreads();          // drains vmcnt + lgkm, flips buffer safely
        buf ^= 1;
    }
    COMPUTE(buf);

    // epilogue: C/D layout col=lane&15, row=(lane>>4)*4+j  [m89]
#pragma unroll
    for (int m = 0; m < 4; ++m) {
#pragma unroll
        for (int n = 0; n < 4; ++n) {
#pragma unroll
            for (int j = 0; j < 4; ++j) {
                int row = wr * 64 + m * 16 + (lane >> 4) * 4 + j;
                int col = wc * 64 + n * 16 + (lane & 15);
                Cbase[(size_t)row * N_DIM + col] = acc[m][n][j];
            }
        }
    }
}

// ---------------- Fallback: round-1 fused kernel ----------------
#define BM 128
#define BN 128
#define BK 64
#define KT (K_DIM / BK)

__device__ __forceinline__ int swz_f(int row, int kelem) {
    return kelem ^ (((row ^ (row >> 3)) & 7) << 3);
}

__global__ __launch_bounds__(256) void grouped_gemm_fused_kernel(
    const float* __restrict__ A, const float* __restrict__ W, float* __restrict__ C)
{
    const int bn = blockIdx.x;
    const int bm = blockIdx.y;
    const int e  = blockIdx.z;
    const int tid  = threadIdx.x;
    const int lane = tid & 63;
    const int wid  = tid >> 6;
    const int wr   = wid >> 1;
    const int wc   = wid & 1;

    __shared__ __align__(16) unsigned short fA[BM * BK];
    __shared__ __align__(16) unsigned short fB[BN * BK];

    const float* Abase = A + ((size_t)e * M_PER_E + (size_t)bm * BM) * K_DIM;
    const float* Wbase = W + (size_t)e * K_DIM * N_DIM + (size_t)bn * BN;
    float*       Cbase = C + ((size_t)e * M_PER_E + (size_t)bm * BM) * N_DIM + (size_t)bn * BN;

    const int arow  = tid >> 4;
    const int acol4 = (tid & 15) * 4;
    const int bkq   = tid >> 4;
    const int bnq   = tid & 15;

    f32x4 acc[4][4];
#pragma unroll
    for (int m = 0; m < 4; ++m)
#pragma unroll
        for (int n = 0; n < 4; ++n) acc[m][n] = (f32x4)0.0f;

    float4v ra[8], rb[8];

    auto LOADT = [&](int kt) {
        const float* ap = Abase + (size_t)arow * K_DIM + kt * BK + acol4;
#pragma unroll
        for (int i = 0; i < 8; ++i)
            ra[i] = *reinterpret_cast<const float4v*>(ap + (size_t)i * 16 * K_DIM);
        const float* bp = Wbase + (size_t)(kt * BK + bkq * 4) * N_DIM + bnq * 4;
#pragma unroll
        for (int i = 0; i < 2; ++i)
#pragma unroll
            for (int r = 0; r < 4; ++r)
                rb[i * 4 + r] = *reinterpret_cast<const float4v*>(bp + (size_t)r * N_DIM + i * 64);
    };

    auto STORET = [&]() {
#pragma unroll
        for (int i = 0; i < 8; ++i) {
            int row = arow + i * 16;
            ushort4v v = cvt4_bf16(ra[i]);
            *reinterpret_cast<ushort4v*>(&fA[row * BK + swz_f(row, acol4)]) = v;
        }
#pragma unroll
        for (int i = 0; i < 2; ++i) {
#pragma unroll
            for (int j = 0; j < 4; ++j) {
                int n = (bnq + i * 16) * 4 + j;
                float4v col;
                col[0] = rb[i * 4 + 0][j];
                col[1] = rb[i * 4 + 1][j];
                col[2] = rb[i * 4 + 2][j];
                col[3] = rb[i * 4 + 3][j];
                ushort4v v = cvt4_bf16(col);
                *reinterpret_cast<ushort4v*>(&fB[n * BK + swz_f(n, bkq * 4)]) = v;
            }
        }
    };

    auto COMPUTE = [&]() {
#pragma unroll
        for (int s = 0; s < 2; ++s) {
            bf16x8 af[4], bfr[4];
            const int ke = s * 32 + (lane >> 4) * 8;
#pragma unroll
            for (int m = 0; m < 4; ++m) {
                int row = wr * 64 + m * 16 + (lane & 15);
                af[m] = *reinterpret_cast<const bf16x8*>(&fA[row * BK + swz_f(row, ke)]);
            }
#pragma unroll
            for (int n = 0; n < 4; ++n) {
                int row = wc * 64 + n * 16 + (lane & 15);
                bfr[n] = *reinterpret_cast<const bf16x8*>(&fB[row * BK + swz_f(row, ke)]);
            }
#pragma unroll
            for (int m = 0; m < 4; ++m)
#pragma unroll
                for (int n = 0; n < 4; ++n)
                    acc[m][n] = __builtin_amdgcn_mfma_f32_16x16x32_bf16(
                        af[m], bfr[n], acc[m][n], 0, 0, 0);
        }
    };

    LOADT(0);
    STORET();
    __syncthreads();
    for (int kt = 0; kt < KT; ++kt) {
        if (kt + 1 < KT) LOADT(kt + 1);
        COMPUTE();
        __syncthreads();
        if (kt + 1 < KT) STORET();
        __syncthreads();
    }

#pragma unroll
    for (int m = 0; m < 4; ++m)
#pragma unroll
        for (int n = 0; n < 4; ++n)
#pragma unroll
            for (int j = 0; j < 4; ++j) {
                int row = wr * 64 + m * 16 + (lane >> 4) * 4 + j;
                int col = wc * 64 + n * 16 + (lane & 15);
                Cbase[(size_t)row * N_DIM + col] = acc[m][n][j];
            }
}

extern "C" void kernel_launch(void* const* d_in, const int* in_sizes, int n_in,
                              void* d_out, int out_size, void* d_ws, size_t ws_size,
                              hipStream_t stream) {
    const float* A = (const float*)d_in[0];
    // d_in[1] = expert_size (static 2048 each) — unused
    const float* W = (const float*)d_in[2];
    float* out = (float*)d_out;

    if (ws_size >= WS_NEEDED) {
        unsigned short* wsA = (unsigned short*)d_ws;
        unsigned short* wsW = wsA + (size_t)A_ELEMS;

        hipLaunchKernelGGL(convertA_kernel, dim3(2048), dim3(256), 0, stream,
                           A, wsA, A_ELEMS / 8);
        hipLaunchKernelGGL(transposeW_kernel, dim3(N_DIM / 64, K_DIM / 64, E_NUM),
                           dim3(256), 0, stream, W, wsW);
        hipLaunchKernelGGL(gemm_bf16_kernel, dim3(8192), dim3(256), 0, stream,
                           wsA, wsW, out);
    } else {
        dim3 grid(N_DIM / BN, M_PER_E / BM, E_NUM);
        hipLaunchKernelGGL(grouped_gemm_fused_kernel, grid, dim3(256), 0, stream,
                           A, W, out);
    }
}

// Round 3
// 474.575 us; speedup vs baseline: 1.2582x; 1.2271x over previous
//
#include <hip/hip_runtime.h>
#include <hip/hip_bf16.h>

// Grouped GEMM: E=16 experts, each [2048x1024] @ [1024x4096], fp32 in/out.
// Round 3:
//   Pass 1a: A fp32 -> bf16 (coalesced)
//   Pass 1b: W [K][N] fp32 -> WT [N][K] bf16 (LDS-tiled transpose)
//   Pass 2 : 256x256 tile, BK=64, 8 waves (2Mx4N), 128 KiB LDS double buffer,
//            global_load_lds w=16 with involution swizzle (linear LDS dest +
//            inverse-swizzled global src + swizzled ds_read_b128),
//            depth-2 prefetch with counted vmcnt(8) (T3+T4), setprio (T5),
//            XCD-bijective block swizzle (T1).

#define E_NUM 16
#define M_PER_E 2048
#define K_DIM 1024
#define N_DIM 4096

#define A_ELEMS (E_NUM * M_PER_E * K_DIM)
#define W_ELEMS (E_NUM * K_DIM * N_DIM)
#define WS_NEEDED ((size_t)A_ELEMS * 2 + (size_t)W_ELEMS * 2)

typedef float  float4v  __attribute__((ext_vector_type(4)));
typedef float  f32x4    __attribute__((ext_vector_type(4)));
typedef short  bf16x8   __attribute__((ext_vector_type(8)));
typedef unsigned short ushort4v __attribute__((ext_vector_type(4)));
typedef unsigned short ushort8v __attribute__((ext_vector_type(8)));

__device__ __forceinline__ ushort4v cvt4_bf16(float4v f) {
    union { __bf16 h[4]; ushort4v u; } x;
#pragma unroll
    for (int j = 0; j < 4; ++j) x.h[j] = (__bf16)f[j];
    return x.u;
}

// ---------------- Pass 1a: A fp32 -> bf16 ----------------
__global__ __launch_bounds__(256) void convertA_kernel(
    const float* __restrict__ A, unsigned short* __restrict__ out, int n8)
{
    int idx = blockIdx.x * 256 + threadIdx.x;
    int stride = gridDim.x * 256;
    for (int i = idx; i < n8; i += stride) {
        float4v a = *reinterpret_cast<const float4v*>(A + (size_t)i * 8);
        float4v b = *reinterpret_cast<const float4v*>(A + (size_t)i * 8 + 4);
        ushort8v v;
        ushort4v va = cvt4_bf16(a), vb = cvt4_bf16(b);
#pragma unroll
        for (int j = 0; j < 4; ++j) { v[j] = va[j]; v[j + 4] = vb[j]; }
        *reinterpret_cast<ushort8v*>(out + (size_t)i * 8) = v;
    }
}

// ---------------- Pass 1b: W [E][K][N] fp32 -> WT [E][N][K] bf16 ----------------
__global__ __launch_bounds__(256) void transposeW_kernel(
    const float* __restrict__ W, unsigned short* __restrict__ WT)
{
    const int nt = blockIdx.x;   // 0..63  (N tiles)
    const int kt = blockIdx.y;   // 0..15  (K tiles)
    const int e  = blockIdx.z;   // 0..15
    const int t  = threadIdx.x;

    __shared__ __align__(16) float T[64 * 64];

    const float* Wb = W + ((size_t)e * K_DIM + (size_t)kt * 64) * N_DIM + nt * 64;

#pragma unroll
    for (int j = 0; j < 4; ++j) {
        int kl = (t >> 4) + j * 16;
        int n4 = t & 15;
        float4v v = *reinterpret_cast<const float4v*>(Wb + (size_t)kl * N_DIM + n4 * 4);
        int sp = n4 ^ ((kl >> 3) & 7);
        *reinterpret_cast<float4v*>(&T[kl * 64 + sp * 4]) = v;
    }
    __syncthreads();

#pragma unroll
    for (int c = 0; c < 2; ++c) {
        int nl = (t >> 3) + c * 32;
        int kc = t & 7;
        ushort8v v;
#pragma unroll
        for (int j = 0; j < 8; ++j) {
            int kl = kc * 8 + j;
            int sp = (nl >> 2) ^ kc;           // (kl>>3)&7 == kc here
            float f = T[kl * 64 + sp * 4 + (nl & 3)];
            union { __bf16 h; unsigned short u; } cv; cv.h = (__bf16)f;
            v[j] = cv.u;
        }
        unsigned short* dst = WT + ((size_t)e * N_DIM + (size_t)nt * 64 + nl) * K_DIM
                              + (size_t)kt * 64 + kc * 8;
        *reinterpret_cast<ushort8v*>(dst) = v;
    }
}

// ---------------- Pass 2: 256^2 bf16 GEMM, depth-2 counted-vmcnt pipeline ----
#define GBM 256
#define GBN 256
#define GBK 64
#define GKT (K_DIM / GBK)   // 16 K-tiles

__global__ __launch_bounds__(512, 2) void gemm_bf16_kernel(
    const unsigned short* __restrict__ A,   // [E*2048][1024] bf16
    const unsigned short* __restrict__ B,   // [E*4096][1024] bf16 (W^T)
    float* __restrict__ C)                  // [E*2048][4096] fp32
{
    // XCD-bijective swizzle over 2048 blocks (2048 % 8 == 0)
    const int bid = blockIdx.x;
    const int swzid = (bid & 7) * (2048 / 8) + (bid >> 3);
    const int e   = swzid >> 7;        // 128 tiles/expert
    const int rem = swzid & 127;
    const int bm  = rem >> 4;          // 0..7
    const int bn  = rem & 15;          // 0..15

    const int tid  = threadIdx.x;
    const int lane = tid & 63;
    const int wid  = tid >> 6;         // 0..7
    const int wm   = wid >> 2;         // 0..1  (128 rows)
    const int wn   = wid & 3;          // 0..3  (64 cols)
    const int lrow = lane & 15;
    const int kq   = lane >> 4;        // 0..3

    // 128 KiB total LDS: 2 bufs x (A 32KB + B 32KB)
    __shared__ __align__(16) unsigned short sA[2][GBM * GBK];
    __shared__ __align__(16) unsigned short sB[2][GBN * GBK];

    const unsigned short* Abase = A + ((size_t)e * M_PER_E + (size_t)bm * GBM) * K_DIM;
    const unsigned short* Bbase = B + ((size_t)e * N_DIM  + (size_t)bn * GBN) * K_DIM;
    float*                Cbase = C + ((size_t)e * M_PER_E + (size_t)bm * GBM) * N_DIM
                                    + (size_t)bn * GBN;

    // Involution swizzle: LDS row = 128B = 8 slots of 16B.
    // phys_slot = logical_chunk ^ (row & 7).
    // gload_lds writes linearly (lane l -> row l>>3, slot l&7), so the global
    // source fetches logical chunk (l&7) ^ ((l>>3)&7)  [row base multiple of 8].
    const int schunk = (lane & 7) ^ ((lane >> 3) & 7);
    const int srow   = lane >> 3;

    auto STAGE = [&](int p, int kt) {
        const unsigned short* ak = Abase + (size_t)kt * GBK + schunk * 8;
        const unsigned short* bk = Bbase + (size_t)kt * GBK + schunk * 8;
#pragma unroll
        for (int i = 0; i < 4; ++i) {
            const int rb = i * 64 + wid * 8;
            __builtin_amdgcn_global_load_lds(
                (const __attribute__((address_space(1))) void*)(ak + (size_t)(rb + srow) * K_DIM),
                (__attribute__((address_space(3))) void*)&sA[p][rb * GBK], 16, 0, 0);
            __builtin_amdgcn_global_load_lds(
                (const __attribute__((address_space(1))) void*)(bk + (size_t)(rb + srow) * K_DIM),
                (__attribute__((address_space(3))) void*)&sB[p][rb * GBK], 16, 0, 0);
        }
    };

    f32x4 acc[8][4];
#pragma unroll
    for (int mf = 0; mf < 8; ++mf)
#pragma unroll
        for (int nf = 0; nf < 4; ++nf) acc[mf][nf] = (f32x4)0.0f;

    bf16x8 af[8], bf[4];

    auto READ = [&](int p, int s) {
        const int slot = (s * 4 + kq) ^ (lrow & 7);
#pragma unroll
        for (int mf = 0; mf < 8; ++mf) {
            int row = wm * 128 + mf * 16 + lrow;
            af[mf] = *reinterpret_cast<const bf16x8*>(&sA[p][row * GBK + slot * 8]);
        }
#pragma unroll
        for (int nf = 0; nf < 4; ++nf) {
            int row = wn * 64 + nf * 16 + lrow;
            bf[nf] = *reinterpret_cast<const bf16x8*>(&sB[p][row * GBK + slot * 8]);
        }
    };

    auto MM = [&]() {
        __builtin_amdgcn_s_setprio(1);
#pragma unroll
        for (int nf = 0; nf < 4; ++nf)
#pragma unroll
            for (int mf = 0; mf < 8; ++mf)
                acc[mf][nf] = __builtin_amdgcn_mfma_f32_16x16x32_bf16(
                    af[mf], bf[nf], acc[mf][nf], 0, 0, 0);
        __builtin_amdgcn_s_setprio(0);
    };

    // prologue: fill both buffers, land tile 0 (8 of 16 loads allowed in flight)
    STAGE(0, 0);
    STAGE(1, 1);
    asm volatile("s_waitcnt vmcnt(8)" ::: "memory");
    __builtin_amdgcn_s_barrier();

#pragma unroll 1
    for (int t = 0; t < GKT; ++t) {
        const int p = t & 1;
        READ(p, 0);
        MM();                               // K 0..31
        READ(p, 1);
        asm volatile("s_waitcnt lgkmcnt(0)" ::: "memory");
        __builtin_amdgcn_s_barrier();       // all waves done reading buf p
        if (t < GKT - 2) STAGE(p, t + 2);   // overwrite freed buffer
        MM();                               // K 32..63
        if (t < GKT - 1) {
            if (t < GKT - 2)
                asm volatile("s_waitcnt vmcnt(8)" ::: "memory");  // tile t+1 landed
            else
                asm volatile("s_waitcnt vmcnt(0)" ::: "memory");
            __builtin_amdgcn_s_barrier();
        }
    }

    // epilogue: C/D layout col=lane&15, row=(lane>>4)*4+j  [m89]
#pragma unroll
    for (int mf = 0; mf < 8; ++mf) {
#pragma unroll
        for (int nf = 0; nf < 4; ++nf) {
#pragma unroll
            for (int j = 0; j < 4; ++j) {
                int row = wm * 128 + mf * 16 + kq * 4 + j;
                int col = wn * 64 + nf * 16 + lrow;
                Cbase[(size_t)row * N_DIM + col] = acc[mf][nf][j];
            }
        }
    }
}

// ---------------- Fallback: round-1 fused kernel ----------------
#define BM 128
#define BN 128
#define BK 64
#define KT (K_DIM / BK)

__device__ __forceinline__ int swz_f(int row, int kelem) {
    return kelem ^ (((row ^ (row >> 3)) & 7) << 3);
}

__global__ __launch_bounds__(256) void grouped_gemm_fused_kernel(
    const float* __restrict__ A, const float* __restrict__ W, float* __restrict__ C)
{
    const int bn = blockIdx.x;
    const int bm = blockIdx.y;
    const int e  = blockIdx.z;
    const int tid  = threadIdx.x;
    const int lane = tid & 63;
    const int wid  = tid >> 6;
    const int wr   = wid >> 1;
    const int wc   = wid & 1;

    __shared__ __align__(16) unsigned short fA[BM * BK];
    __shared__ __align__(16) unsigned short fB[BN * BK];

    const float* Abase = A + ((size_t)e * M_PER_E + (size_t)bm * BM) * K_DIM;
    const float* Wbase = W + (size_t)e * K_DIM * N_DIM + (size_t)bn * BN;
    float*       Cbase = C + ((size_t)e * M_PER_E + (size_t)bm * BM) * N_DIM + (size_t)bn * BN;

    const int arow  = tid >> 4;
    const int acol4 = (tid & 15) * 4;
    const int bkq   = tid >> 4;
    const int bnq   = tid & 15;

    f32x4 acc[4][4];
#pragma unroll
    for (int m = 0; m < 4; ++m)
#pragma unroll
        for (int n = 0; n < 4; ++n) acc[m][n] = (f32x4)0.0f;

    float4v ra[8], rb[8];

    auto LOADT = [&](int kt) {
        const float* ap = Abase + (size_t)arow * K_DIM + kt * BK + acol4;
#pragma unroll
        for (int i = 0; i < 8; ++i)
            ra[i] = *reinterpret_cast<const float4v*>(ap + (size_t)i * 16 * K_DIM);
        const float* bp = Wbase + (size_t)(kt * BK + bkq * 4) * N_DIM + bnq * 4;
#pragma unroll
        for (int i = 0; i < 2; ++i)
#pragma unroll
            for (int r = 0; r < 4; ++r)
                rb[i * 4 + r] = *reinterpret_cast<const float4v*>(bp + (size_t)r * N_DIM + i * 64);
    };

    auto STORET = [&]() {
#pragma unroll
        for (int i = 0; i < 8; ++i) {
            int row = arow + i * 16;
            ushort4v v = cvt4_bf16(ra[i]);
            *reinterpret_cast<ushort4v*>(&fA[row * BK + swz_f(row, acol4)]) = v;
        }
#pragma unroll
        for (int i = 0; i < 2; ++i) {
#pragma unroll
            for (int j = 0; j < 4; ++j) {
                int n = (bnq + i * 16) * 4 + j;
                float4v col;
                col[0] = rb[i * 4 + 0][j];
                col[1] = rb[i * 4 + 1][j];
                col[2] = rb[i * 4 + 2][j];
                col[3] = rb[i * 4 + 3][j];
                ushort4v v = cvt4_bf16(col);
                *reinterpret_cast<ushort4v*>(&fB[n * BK + swz_f(n, bkq * 4)]) = v;
            }
        }
    };

    auto COMPUTE = [&]() {
#pragma unroll
        for (int s = 0; s < 2; ++s) {
            bf16x8 af[4], bfr[4];
            const int ke = s * 32 + (lane >> 4) * 8;
#pragma unroll
            for (int m = 0; m < 4; ++m) {
                int row = wr * 64 + m * 16 + (lane & 15);
                af[m] = *reinterpret_cast<const bf16x8*>(&fA[row * BK + swz_f(row, ke)]);
            }
#pragma unroll
            for (int n = 0; n < 4; ++n) {
                int row = wc * 64 + n * 16 + (lane & 15);
                bfr[n] = *reinterpret_cast<const bf16x8*>(&fB[row * BK + swz_f(row, ke)]);
            }
#pragma unroll
            for (int m = 0; m < 4; ++m)
#pragma unroll
                for (int n = 0; n < 4; ++n)
                    acc[m][n] = __builtin_amdgcn_mfma_f32_16x16x32_bf16(
                        af[m], bfr[n], acc[m][n], 0, 0, 0);
        }
    };

    LOADT(0);
    STORET();
    __syncthreads();
    for (int kt = 0; kt < KT; ++kt) {
        if (kt + 1 < KT) LOADT(kt + 1);
        COMPUTE();
        __syncthreads();
        if (kt + 1 < KT) STORET();
        __syncthreads();
    }

#pragma unroll
    for (int m = 0; m < 4; ++m)
#pragma unroll
        for (int n = 0; n < 4; ++n)
#pragma unroll
            for (int j = 0; j < 4; ++j) {
                int row = wr * 64 + m * 16 + (lane >> 4) * 4 + j;
                int col = wc * 64 + n * 16 + (lane & 15);
                Cbase[(size_t)row * N_DIM + col] = acc[m][n][j];
            }
}

extern "C" void kernel_launch(void* const* d_in, const int* in_sizes, int n_in,
                              void* d_out, int out_size, void* d_ws, size_t ws_size,
                              hipStream_t stream) {
    const float* A = (const float*)d_in[0];
    // d_in[1] = expert_size (static 2048 each) — unused
    const float* W = (const float*)d_in[2];
    float* out = (float*)d_out;

    if (ws_size >= WS_NEEDED) {
        unsigned short* wsA = (unsigned short*)d_ws;
        unsigned short* wsW = wsA + (size_t)A_ELEMS;

        hipLaunchKernelGGL(convertA_kernel, dim3(2048), dim3(256), 0, stream,
                           A, wsA, A_ELEMS / 8);
        hipLaunchKernelGGL(transposeW_kernel, dim3(N_DIM / 64, K_DIM / 64, E_NUM),
                           dim3(256), 0, stream, W, wsW);
        hipLaunchKernelGGL(gemm_bf16_kernel, dim3(2048), dim3(512), 0, stream,
                           wsA, wsW, out);
    } else {
        dim3 grid(N_DIM / BN, M_PER_E / BM, E_NUM);
        hipLaunchKernelGGL(grouped_gemm_fused_kernel, grid, dim3(256), 0, stream,
                           A, W, out);
    }
}

// Round 4
// 470.323 us; speedup vs baseline: 1.2696x; 1.0090x over previous
//
#include <hip/hip_runtime.h>
#include <hip/hip_bf16.h>

// Grouped GEMM: E=16 experts, each [2048x1024] @ [1024x4096], fp32 in/out.
// Round 4:
//   Pass 1a: A fp32 -> bf16 (coalesced)
//   Pass 1b: W [K][N] fp32 -> WT [N][K] bf16 (LDS-tiled transpose)
//   Pass 2 : 256x256 tile, BK=64, 8 waves (2Mx4N), 128 KiB LDS double buffer,
//            whole-tile register fragments (LDS caps us at 1 block/CU, so
//            VGPRs are free), 4 MFMA quadrant clusters of 16 w/ setprio,
//            counted vmcnt(8) depth-2 pipeline, involution LDS swizzle,
//            XCD-bijective block swizzle.

#define E_NUM 16
#define M_PER_E 2048
#define K_DIM 1024
#define N_DIM 4096

#define A_ELEMS (E_NUM * M_PER_E * K_DIM)
#define W_ELEMS (E_NUM * K_DIM * N_DIM)
#define WS_NEEDED ((size_t)A_ELEMS * 2 + (size_t)W_ELEMS * 2)

typedef float  float4v  __attribute__((ext_vector_type(4)));
typedef float  f32x4    __attribute__((ext_vector_type(4)));
typedef short  bf16x8   __attribute__((ext_vector_type(8)));
typedef unsigned short ushort4v __attribute__((ext_vector_type(4)));
typedef unsigned short ushort8v __attribute__((ext_vector_type(8)));

__device__ __forceinline__ ushort4v cvt4_bf16(float4v f) {
    union { __bf16 h[4]; ushort4v u; } x;
#pragma unroll
    for (int j = 0; j < 4; ++j) x.h[j] = (__bf16)f[j];
    return x.u;
}

// ---------------- Pass 1a: A fp32 -> bf16 ----------------
__global__ __launch_bounds__(256) void convertA_kernel(
    const float* __restrict__ A, unsigned short* __restrict__ out, int n8)
{
    int idx = blockIdx.x * 256 + threadIdx.x;
    int stride = gridDim.x * 256;
    for (int i = idx; i < n8; i += stride) {
        float4v a = *reinterpret_cast<const float4v*>(A + (size_t)i * 8);
        float4v b = *reinterpret_cast<const float4v*>(A + (size_t)i * 8 + 4);
        ushort8v v;
        ushort4v va = cvt4_bf16(a), vb = cvt4_bf16(b);
#pragma unroll
        for (int j = 0; j < 4; ++j) { v[j] = va[j]; v[j + 4] = vb[j]; }
        *reinterpret_cast<ushort8v*>(out + (size_t)i * 8) = v;
    }
}

// ---------------- Pass 1b: W [E][K][N] fp32 -> WT [E][N][K] bf16 ----------------
__global__ __launch_bounds__(256) void transposeW_kernel(
    const float* __restrict__ W, unsigned short* __restrict__ WT)
{
    const int nt = blockIdx.x;   // 0..63  (N tiles)
    const int kt = blockIdx.y;   // 0..15  (K tiles)
    const int e  = blockIdx.z;   // 0..15
    const int t  = threadIdx.x;

    __shared__ __align__(16) float T[64 * 64];

    const float* Wb = W + ((size_t)e * K_DIM + (size_t)kt * 64) * N_DIM + nt * 64;

#pragma unroll
    for (int j = 0; j < 4; ++j) {
        int kl = (t >> 4) + j * 16;
        int n4 = t & 15;
        float4v v = *reinterpret_cast<const float4v*>(Wb + (size_t)kl * N_DIM + n4 * 4);
        int sp = n4 ^ ((kl >> 3) & 7);
        *reinterpret_cast<float4v*>(&T[kl * 64 + sp * 4]) = v;
    }
    __syncthreads();

#pragma unroll
    for (int c = 0; c < 2; ++c) {
        int nl = (t >> 3) + c * 32;
        int kc = t & 7;
        ushort8v v;
#pragma unroll
        for (int j = 0; j < 8; ++j) {
            int kl = kc * 8 + j;
            int sp = (nl >> 2) ^ kc;           // (kl>>3)&7 == kc here
            float f = T[kl * 64 + sp * 4 + (nl & 3)];
            union { __bf16 h; unsigned short u; } cv; cv.h = (__bf16)f;
            v[j] = cv.u;
        }
        unsigned short* dst = WT + ((size_t)e * N_DIM + (size_t)nt * 64 + nl) * K_DIM
                              + (size_t)kt * 64 + kc * 8;
        *reinterpret_cast<ushort8v*>(dst) = v;
    }
}

// ---------------- Pass 2: 256^2 bf16 GEMM, reg-tile + quadrant clusters ------
#define GBM 256
#define GBN 256
#define GBK 64
#define GKT (K_DIM / GBK)   // 16 K-tiles

__global__ __launch_bounds__(512, 2) void gemm_bf16_kernel(
    const unsigned short* __restrict__ A,   // [E*2048][1024] bf16
    const unsigned short* __restrict__ B,   // [E*4096][1024] bf16 (W^T)
    float* __restrict__ C)                  // [E*2048][4096] fp32
{
    // XCD-bijective swizzle over 2048 blocks (2048 % 8 == 0)
    const int bid = blockIdx.x;
    const int swzid = (bid & 7) * (2048 / 8) + (bid >> 3);
    const int e   = swzid >> 7;        // 128 tiles/expert
    const int rem = swzid & 127;
    const int bm  = rem >> 4;          // 0..7
    const int bn  = rem & 15;          // 0..15

    const int tid  = threadIdx.x;
    const int lane = tid & 63;
    const int wid  = tid >> 6;         // 0..7
    const int wm   = wid >> 2;         // 0..1  (128 rows)
    const int wn   = wid & 3;          // 0..3  (64 cols)
    const int lrow = lane & 15;
    const int kq   = lane >> 4;        // 0..3

    // 128 KiB total LDS: 2 bufs x (A 32KB + B 32KB) -> 1 block/CU
    __shared__ __align__(16) unsigned short sA[2][GBM * GBK];
    __shared__ __align__(16) unsigned short sB[2][GBN * GBK];

    const unsigned short* Abase = A + ((size_t)e * M_PER_E + (size_t)bm * GBM) * K_DIM;
    const unsigned short* Bbase = B + ((size_t)e * N_DIM  + (size_t)bn * GBN) * K_DIM;
    float*                Cbase = C + ((size_t)e * M_PER_E + (size_t)bm * GBM) * N_DIM
                                    + (size_t)bn * GBN;

    // Involution swizzle: LDS row = 128B = 8 slots of 16B.
    // phys_slot = logical_chunk ^ (row & 7); gload_lds writes linearly, so the
    // global source fetches logical chunk (l&7) ^ ((l>>3)&7).
    const int schunk = (lane & 7) ^ ((lane >> 3) & 7);
    const int srow   = lane >> 3;

    auto STAGE = [&](int p, int kt) {
        const unsigned short* ak = Abase + (size_t)kt * GBK + schunk * 8;
        const unsigned short* bk = Bbase + (size_t)kt * GBK + schunk * 8;
#pragma unroll
        for (int i = 0; i < 4; ++i) {
            const int rb = i * 64 + wid * 8;
            __builtin_amdgcn_global_load_lds(
                (const __attribute__((address_space(1))) void*)(ak + (size_t)(rb + srow) * K_DIM),
                (__attribute__((address_space(3))) void*)&sA[p][rb * GBK], 16, 0, 0);
            __builtin_amdgcn_global_load_lds(
                (const __attribute__((address_space(1))) void*)(bk + (size_t)(rb + srow) * K_DIM),
                (__attribute__((address_space(3))) void*)&sB[p][rb * GBK], 16, 0, 0);
        }
    };

    f32x4 acc[8][4];
#pragma unroll
    for (int mf = 0; mf < 8; ++mf)
#pragma unroll
        for (int nf = 0; nf < 4; ++nf) acc[mf][nf] = (f32x4)0.0f;

    bf16x8 af[8][2], bf[4][2];

    // whole-tile fragment read; mh=0 operands + all B first so the first
    // MFMA cluster can start after 16 of the 24 ds_read_b128.
    auto READ_ALL = [&](int p) {
#pragma unroll
        for (int s = 0; s < 2; ++s) {
            const int slot = (s * 4 + kq) ^ (lrow & 7);
#pragma unroll
            for (int mf = 0; mf < 4; ++mf) {
                int row = wm * 128 + mf * 16 + lrow;
                af[mf][s] = *reinterpret_cast<const bf16x8*>(&sA[p][row * GBK + slot * 8]);
            }
#pragma unroll
            for (int nf = 0; nf < 4; ++nf) {
                int row = wn * 64 + nf * 16 + lrow;
                bf[nf][s] = *reinterpret_cast<const bf16x8*>(&sB[p][row * GBK + slot * 8]);
            }
        }
#pragma unroll
        for (int s = 0; s < 2; ++s) {
            const int slot = (s * 4 + kq) ^ (lrow & 7);
#pragma unroll
            for (int mf = 4; mf < 8; ++mf) {
                int row = wm * 128 + mf * 16 + lrow;
                af[mf][s] = *reinterpret_cast<const bf16x8*>(&sA[p][row * GBK + slot * 8]);
            }
        }
    };

    // one C-quadrant: 4 m-frags x 2 n-frags x 2 k-slices = 16 MFMA
    auto MMQ = [&](int mh, int nh) {
        __builtin_amdgcn_s_setprio(1);
#pragma unroll
        for (int s = 0; s < 2; ++s)
#pragma unroll
            for (int nf = nh * 2; nf < nh * 2 + 2; ++nf)
#pragma unroll
                for (int mf = mh * 4; mf < mh * 4 + 4; ++mf)
                    acc[mf][nf] = __builtin_amdgcn_mfma_f32_16x16x32_bf16(
                        af[mf][s], bf[nf][s], acc[mf][nf], 0, 0, 0);
        __builtin_amdgcn_s_setprio(0);
    };

    // prologue: fill both buffers; tile 0 must be resident (8 newest may fly)
    STAGE(0, 0);
    STAGE(1, 1);
    asm volatile("s_waitcnt vmcnt(8)" ::: "memory");
    __builtin_amdgcn_s_barrier();

#pragma unroll 1
    for (int t = 0; t < GKT; ++t) {
        const int p = t & 1;
        READ_ALL(p);                         // 24 ds_read_b128
        MMQ(0, 0); MMQ(0, 1);                // hides ds_read drain (counted lgkm)
        asm volatile("s_waitcnt lgkmcnt(0)" ::: "memory");
        __builtin_amdgcn_s_barrier();        // buf p fully consumed block-wide
        if (t < GKT - 2) STAGE(p, t + 2);    // overwrite freed buffer, max lead
        MMQ(1, 0); MMQ(1, 1);
        if (t < GKT - 1) {
            if (t < GKT - 2)
                asm volatile("s_waitcnt vmcnt(8)" ::: "memory");  // t+1 resident
            else
                asm volatile("s_waitcnt vmcnt(0)" ::: "memory");
            __builtin_amdgcn_s_barrier();
        }
    }

    // epilogue: C/D layout col=lane&15, row=(lane>>4)*4+j  [m89]
#pragma unroll
    for (int mf = 0; mf < 8; ++mf) {
#pragma unroll
        for (int nf = 0; nf < 4; ++nf) {
#pragma unroll
            for (int j = 0; j < 4; ++j) {
                int row = wm * 128 + mf * 16 + kq * 4 + j;
                int col = wn * 64 + nf * 16 + lrow;
                Cbase[(size_t)row * N_DIM + col] = acc[mf][nf][j];
            }
        }
    }
}

// ---------------- Fallback: round-1 fused kernel ----------------
#define BM 128
#define BN 128
#define BK 64
#define KT (K_DIM / BK)

__device__ __forceinline__ int swz_f(int row, int kelem) {
    return kelem ^ (((row ^ (row >> 3)) & 7) << 3);
}

__global__ __launch_bounds__(256) void grouped_gemm_fused_kernel(
    const float* __restrict__ A, const float* __restrict__ W, float* __restrict__ C)
{
    const int bn = blockIdx.x;
    const int bm = blockIdx.y;
    const int e  = blockIdx.z;
    const int tid  = threadIdx.x;
    const int lane = tid & 63;
    const int wid  = tid >> 6;
    const int wr   = wid >> 1;
    const int wc   = wid & 1;

    __shared__ __align__(16) unsigned short fA[BM * BK];
    __shared__ __align__(16) unsigned short fB[BN * BK];

    const float* Abase = A + ((size_t)e * M_PER_E + (size_t)bm * BM) * K_DIM;
    const float* Wbase = W + (size_t)e * K_DIM * N_DIM + (size_t)bn * BN;
    float*       Cbase = C + ((size_t)e * M_PER_E + (size_t)bm * BM) * N_DIM + (size_t)bn * BN;

    const int arow  = tid >> 4;
    const int acol4 = (tid & 15) * 4;
    const int bkq   = tid >> 4;
    const int bnq   = tid & 15;

    f32x4 acc[4][4];
#pragma unroll
    for (int m = 0; m < 4; ++m)
#pragma unroll
        for (int n = 0; n < 4; ++n) acc[m][n] = (f32x4)0.0f;

    float4v ra[8], rb[8];

    auto LOADT = [&](int kt) {
        const float* ap = Abase + (size_t)arow * K_DIM + kt * BK + acol4;
#pragma unroll
        for (int i = 0; i < 8; ++i)
            ra[i] = *reinterpret_cast<const float4v*>(ap + (size_t)i * 16 * K_DIM);
        const float* bp = Wbase + (size_t)(kt * BK + bkq * 4) * N_DIM + bnq * 4;
#pragma unroll
        for (int i = 0; i < 2; ++i)
#pragma unroll
            for (int r = 0; r < 4; ++r)
                rb[i * 4 + r] = *reinterpret_cast<const float4v*>(bp + (size_t)r * N_DIM + i * 64);
    };

    auto STORET = [&]() {
#pragma unroll
        for (int i = 0; i < 8; ++i) {
            int row = arow + i * 16;
            ushort4v v = cvt4_bf16(ra[i]);
            *reinterpret_cast<ushort4v*>(&fA[row * BK + swz_f(row, acol4)]) = v;
        }
#pragma unroll
        for (int i = 0; i < 2; ++i) {
#pragma unroll
            for (int j = 0; j < 4; ++j) {
                int n = (bnq + i * 16) * 4 + j;
                float4v col;
                col[0] = rb[i * 4 + 0][j];
                col[1] = rb[i * 4 + 1][j];
                col[2] = rb[i * 4 + 2][j];
                col[3] = rb[i * 4 + 3][j];
                ushort4v v = cvt4_bf16(col);
                *reinterpret_cast<ushort4v*>(&fB[n * BK + swz_f(n, bkq * 4)]) = v;
            }
        }
    };

    auto COMPUTE = [&]() {
#pragma unroll
        for (int s = 0; s < 2; ++s) {
            bf16x8 af[4], bfr[4];
            const int ke = s * 32 + (lane >> 4) * 8;
#pragma unroll
            for (int m = 0; m < 4; ++m) {
                int row = wr * 64 + m * 16 + (lane & 15);
                af[m] = *reinterpret_cast<const bf16x8*>(&fA[row * BK + swz_f(row, ke)]);
            }
#pragma unroll
            for (int n = 0; n < 4; ++n) {
                int row = wc * 64 + n * 16 + (lane & 15);
                bfr[n] = *reinterpret_cast<const bf16x8*>(&fB[row * BK + swz_f(row, ke)]);
            }
#pragma unroll
            for (int m = 0; m < 4; ++m)
#pragma unroll
                for (int n = 0; n < 4; ++n)
                    acc[m][n] = __builtin_amdgcn_mfma_f32_16x16x32_bf16(
                        af[m], bfr[n], acc[m][n], 0, 0, 0);
        }
    };

    LOADT(0);
    STORET();
    __syncthreads();
    for (int kt = 0; kt < KT; ++kt) {
        if (kt + 1 < KT) LOADT(kt + 1);
        COMPUTE();
        __syncthreads();
        if (kt + 1 < KT) STORET();
        __syncthreads();
    }

#pragma unroll
    for (int m = 0; m < 4; ++m)
#pragma unroll
        for (int n = 0; n < 4; ++n)
#pragma unroll
            for (int j = 0; j < 4; ++j) {
                int row = wr * 64 + m * 16 + (lane >> 4) * 4 + j;
                int col = wc * 64 + n * 16 + (lane & 15);
                Cbase[(size_t)row * N_DIM + col] = acc[m][n][j];
            }
}

extern "C" void kernel_launch(void* const* d_in, const int* in_sizes, int n_in,
                              void* d_out, int out_size, void* d_ws, size_t ws_size,
                              hipStream_t stream) {
    const float* A = (const float*)d_in[0];
    // d_in[1] = expert_size (static 2048 each) — unused
    const float* W = (const float*)d_in[2];
    float* out = (float*)d_out;

    if (ws_size >= WS_NEEDED) {
        unsigned short* wsA = (unsigned short*)d_ws;
        unsigned short* wsW = wsA + (size_t)A_ELEMS;

        hipLaunchKernelGGL(convertA_kernel, dim3(2048), dim3(256), 0, stream,
                           A, wsA, A_ELEMS / 8);
        hipLaunchKernelGGL(transposeW_kernel, dim3(N_DIM / 64, K_DIM / 64, E_NUM),
                           dim3(256), 0, stream, W, wsW);
        hipLaunchKernelGGL(gemm_bf16_kernel, dim3(2048), dim3(512), 0, stream,
                           wsA, wsW, out);
    } else {
        dim3 grid(N_DIM / BN, M_PER_E / BM, E_NUM);
        hipLaunchKernelGGL(grouped_gemm_fused_kernel, grid, dim3(256), 0, stream,
                           A, W, out);
    }
}

// Round 5
// 462.771 us; speedup vs baseline: 1.2903x; 1.0163x over previous
//
#include <hip/hip_runtime.h>
#include <hip/hip_bf16.h>

// Grouped GEMM: E=16 experts, each [2048x1024] @ [1024x4096], fp32 in/out.
// Round 5:
//   Pass 1a: A fp32 -> bf16 (coalesced)
//   Pass 1b: W [K][N] fp32 -> WT [N][K] bf16 (LDS-tiled transpose)
//   Pass 2 : 256x256 tile, BK=64, 8 waves (2Mx4N), 128 KiB LDS double buffer,
//            full 8-phase schedule (T3+T4): per phase {quadrant ds_reads ||
//            1 half-tile gload_lds -> barrier -> lgkm(0) -> setprio ->
//            16 MFMA -> barrier}, counted vmcnt(4) at P4/P8 only,
//            involution LDS swizzle (conflict-free), XCD-bijective swizzle.

#define E_NUM 16
#define M_PER_E 2048
#define K_DIM 1024
#define N_DIM 4096

#define A_ELEMS (E_NUM * M_PER_E * K_DIM)
#define W_ELEMS (E_NUM * K_DIM * N_DIM)
#define WS_NEEDED ((size_t)A_ELEMS * 2 + (size_t)W_ELEMS * 2)

typedef float  float4v  __attribute__((ext_vector_type(4)));
typedef float  f32x4    __attribute__((ext_vector_type(4)));
typedef short  bf16x8   __attribute__((ext_vector_type(8)));
typedef unsigned short ushort4v __attribute__((ext_vector_type(4)));
typedef unsigned short ushort8v __attribute__((ext_vector_type(8)));

__device__ __forceinline__ ushort4v cvt4_bf16(float4v f) {
    union { __bf16 h[4]; ushort4v u; } x;
#pragma unroll
    for (int j = 0; j < 4; ++j) x.h[j] = (__bf16)f[j];
    return x.u;
}

// ---------------- Pass 1a: A fp32 -> bf16 ----------------
__global__ __launch_bounds__(256) void convertA_kernel(
    const float* __restrict__ A, unsigned short* __restrict__ out, int n8)
{
    int idx = blockIdx.x * 256 + threadIdx.x;
    int stride = gridDim.x * 256;
    for (int i = idx; i < n8; i += stride) {
        float4v a = *reinterpret_cast<const float4v*>(A + (size_t)i * 8);
        float4v b = *reinterpret_cast<const float4v*>(A + (size_t)i * 8 + 4);
        ushort8v v;
        ushort4v va = cvt4_bf16(a), vb = cvt4_bf16(b);
#pragma unroll
        for (int j = 0; j < 4; ++j) { v[j] = va[j]; v[j + 4] = vb[j]; }
        *reinterpret_cast<ushort8v*>(out + (size_t)i * 8) = v;
    }
}

// ---------------- Pass 1b: W [E][K][N] fp32 -> WT [E][N][K] bf16 ----------------
__global__ __launch_bounds__(256) void transposeW_kernel(
    const float* __restrict__ W, unsigned short* __restrict__ WT)
{
    const int nt = blockIdx.x;   // 0..63  (N tiles)
    const int kt = blockIdx.y;   // 0..15  (K tiles)
    const int e  = blockIdx.z;   // 0..15
    const int t  = threadIdx.x;

    __shared__ __align__(16) float T[64 * 64];

    const float* Wb = W + ((size_t)e * K_DIM + (size_t)kt * 64) * N_DIM + nt * 64;

#pragma unroll
    for (int j = 0; j < 4; ++j) {
        int kl = (t >> 4) + j * 16;
        int n4 = t & 15;
        float4v v = *reinterpret_cast<const float4v*>(Wb + (size_t)kl * N_DIM + n4 * 4);
        int sp = n4 ^ ((kl >> 3) & 7);
        *reinterpret_cast<float4v*>(&T[kl * 64 + sp * 4]) = v;
    }
    __syncthreads();

#pragma unroll
    for (int c = 0; c < 2; ++c) {
        int nl = (t >> 3) + c * 32;
        int kc = t & 7;
        ushort8v v;
#pragma unroll
        for (int j = 0; j < 8; ++j) {
            int kl = kc * 8 + j;
            int sp = (nl >> 2) ^ kc;           // (kl>>3)&7 == kc here
            float f = T[kl * 64 + sp * 4 + (nl & 3)];
            union { __bf16 h; unsigned short u; } cv; cv.h = (__bf16)f;
            v[j] = cv.u;
        }
        unsigned short* dst = WT + ((size_t)e * N_DIM + (size_t)nt * 64 + nl) * K_DIM
                              + (size_t)kt * 64 + kc * 8;
        *reinterpret_cast<ushort8v*>(dst) = v;
    }
}

// ---------------- Pass 2: 256^2 bf16 GEMM, 8-phase pipeline ------------------
#define GBM 256
#define GBN 256
#define GBK 64
#define GKT (K_DIM / GBK)   // 16 K-tiles, 8 iters of 2

#define BAR()   __builtin_amdgcn_s_barrier()
#define LGKM0() asm volatile("s_waitcnt lgkmcnt(0)" ::: "memory")

__global__ __launch_bounds__(512, 2) void gemm_bf16_kernel(
    const unsigned short* __restrict__ A,   // [E*2048][1024] bf16
    const unsigned short* __restrict__ B,   // [E*4096][1024] bf16 (W^T)
    float* __restrict__ C)                  // [E*2048][4096] fp32
{
    // XCD-bijective swizzle over 2048 blocks (2048 % 8 == 0)
    const int bid = blockIdx.x;
    const int swzid = (bid & 7) * (2048 / 8) + (bid >> 3);
    const int e   = swzid >> 7;        // 128 tiles/expert
    const int rem = swzid & 127;
    const int bm  = rem >> 4;          // 0..7
    const int bn  = rem & 15;          // 0..15

    const int tid  = threadIdx.x;
    const int lane = tid & 63;
    const int wid  = tid >> 6;         // 0..7
    const int wm   = wid >> 2;         // 0..1  (128 rows)
    const int wn   = wid & 3;          // 0..3  (64 cols)
    const int lrow = lane & 15;
    const int kq   = lane >> 4;        // 0..3

    // 128 KiB: 2 bufs x (A 32KB + B 32KB); halves = 128 rows each
    __shared__ __align__(16) unsigned short sA[2][GBM * GBK];
    __shared__ __align__(16) unsigned short sB[2][GBN * GBK];

    const unsigned short* Abase = A + ((size_t)e * M_PER_E + (size_t)bm * GBM) * K_DIM;
    const unsigned short* Bbase = B + ((size_t)e * N_DIM  + (size_t)bn * GBN) * K_DIM;
    float*                Cbase = C + ((size_t)e * M_PER_E + (size_t)bm * GBM) * N_DIM
                                    + (size_t)bn * GBN;

    // Involution swizzle: LDS row = 128B = 8 slots of 16B.
    // phys_slot = logical_chunk ^ (row & 7); gload_lds writes linearly, so the
    // global source fetches logical chunk (l&7) ^ ((l>>3)&7).
    const int schunk = (lane & 7) ^ ((lane >> 3) & 7);
    const int srow   = lane >> 3;

    // stage one half-tile (128 rows x 64 k) of A or B: 2 gload_lds per thread
    auto STAGE_A = [&](int t, int h) {
        const unsigned short* g = Abase + (size_t)t * GBK + schunk * 8;
#pragma unroll
        for (int j = 0; j < 2; ++j) {
            const int rb = h * 128 + (wid * 2 + j) * 8;
            __builtin_amdgcn_global_load_lds(
                (const __attribute__((address_space(1))) void*)(g + (size_t)(rb + srow) * K_DIM),
                (__attribute__((address_space(3))) void*)&sA[t & 1][rb * GBK], 16, 0, 0);
        }
    };
    auto STAGE_B = [&](int t, int h) {
        const unsigned short* g = Bbase + (size_t)t * GBK + schunk * 8;
#pragma unroll
        for (int j = 0; j < 2; ++j) {
            const int rb = h * 128 + (wid * 2 + j) * 8;
            __builtin_amdgcn_global_load_lds(
                (const __attribute__((address_space(1))) void*)(g + (size_t)(rb + srow) * K_DIM),
                (__attribute__((address_space(3))) void*)&sB[t & 1][rb * GBK], 16, 0, 0);
        }
    };

    f32x4 acc[8][4];
#pragma unroll
    for (int mf = 0; mf < 8; ++mf)
#pragma unroll
        for (int nf = 0; nf < 4; ++nf) acc[mf][nf] = (f32x4)0.0f;

    bf16x8 af[4][2];   // current A quadrant (4 m-frags x 2 k-slices)
    bf16x8 bf[4][2];   // full B panel (4 n-frags x 2 k-slices)

    auto READ_A = [&](int p, int mh) {   // af <- A-half quadrant mh
#pragma unroll
        for (int s = 0; s < 2; ++s) {
            const int slot = (s * 4 + kq) ^ (lrow & 7);
#pragma unroll
            for (int mf = 0; mf < 4; ++mf) {
                int row = wm * 128 + mh * 64 + mf * 16 + lrow;
                af[mf][s] = *reinterpret_cast<const bf16x8*>(&sA[p][row * GBK + slot * 8]);
            }
        }
    };
    auto READ_B = [&](int p, int bh) {   // bf[bh*2..+1]
#pragma unroll
        for (int s = 0; s < 2; ++s) {
            const int slot = (s * 4 + kq) ^ (lrow & 7);
#pragma unroll
            for (int nf = 0; nf < 2; ++nf) {
                int row = wn * 64 + (bh * 2 + nf) * 16 + lrow;
                bf[bh * 2 + nf][s] = *reinterpret_cast<const bf16x8*>(&sB[p][row * GBK + slot * 8]);
            }
        }
    };

    auto MMQ = [&](int mh, int nh) {     // 16 MFMA, one C-quadrant slice
        __builtin_amdgcn_s_setprio(1);
#pragma unroll
        for (int s = 0; s < 2; ++s)
#pragma unroll
            for (int nf = nh * 2; nf < nh * 2 + 2; ++nf)
#pragma unroll
                for (int mf = 0; mf < 4; ++mf)
                    acc[mh * 4 + mf][nf] = __builtin_amdgcn_mfma_f32_16x16x32_bf16(
                        af[mf][s], bf[nf][s], acc[mh * 4 + mf][nf], 0, 0, 0);
        __builtin_amdgcn_s_setprio(0);
    };

    // ---- prologue: stage tile0 fully + B0(1),A0(1); require tile0 resident
    STAGE_B(0, 0); STAGE_A(0, 0); STAGE_A(0, 1); STAGE_B(0, 1);
    STAGE_B(1, 0); STAGE_A(1, 0);
    asm volatile("s_waitcnt vmcnt(4)" ::: "memory");
    BAR();

#pragma unroll 1
    for (int i = 0; i < GKT / 2; ++i) {
        const int u = 2 * i;           // even tile -> buf0
        const int v = 2 * i + 1;       // odd tile  -> buf1
        // ---- P1: tile u, Q(0,0)
        READ_A(0, 0); READ_B(0, 0);
        STAGE_A(v, 1);                         // A1(v): A(v-2) freed last iter P7
        BAR(); LGKM0(); MMQ(0, 0); BAR();
        // ---- P2: Q(0,1)
        READ_B(0, 1);
        STAGE_B(v, 1);                         // B1(v): B(v-2) freed last iter P6
        BAR(); LGKM0(); MMQ(0, 1); BAR();
        // ---- P3: Q(1,0)
        READ_A(0, 1);
        if (u + 2 < GKT) STAGE_B(u + 2, 0);    // B(u) fully read after P2
        BAR(); LGKM0(); MMQ(1, 0); BAR();
        // ---- P4: Q(1,1); check tile v resident
        if (u + 2 < GKT) STAGE_A(u + 2, 0);    // A(u) fully read after P3
        BAR(); MMQ(1, 1);
        if (i < GKT / 2 - 1)
            asm volatile("s_waitcnt vmcnt(4)" ::: "memory");
        else
            asm volatile("s_waitcnt vmcnt(0)" ::: "memory");
        BAR();
        // ---- P5: tile v, Q(0,0)
        READ_A(1, 0); READ_B(1, 0);
        if (u + 2 < GKT) STAGE_A(u + 2, 1);    // A1(u+2): A(u) half1 read done P3
        BAR(); LGKM0(); MMQ(0, 0); BAR();
        // ---- P6: Q(0,1)
        READ_B(1, 1);
        if (u + 2 < GKT) STAGE_B(u + 2, 1);
        BAR(); LGKM0(); MMQ(0, 1); BAR();
        // ---- P7: Q(1,0)
        READ_A(1, 1);
        if (v + 2 < GKT) STAGE_B(v + 2, 0);    // B(v) fully read after P6
        BAR(); LGKM0(); MMQ(1, 0); BAR();
        // ---- P8: Q(1,1); check tile u+2 resident
        if (v + 2 < GKT) STAGE_A(v + 2, 0);    // A(v) fully read after P7
        BAR(); MMQ(1, 1);
        if (i < GKT / 2 - 1) {
            asm volatile("s_waitcnt vmcnt(4)" ::: "memory");
            BAR();
        }
    }

    // epilogue: C/D layout col=lane&15, row=(lane>>4)*4+j  [m89]
#pragma unroll
    for (int mf = 0; mf < 8; ++mf) {
#pragma unroll
        for (int nf = 0; nf < 4; ++nf) {
#pragma unroll
            for (int j = 0; j < 4; ++j) {
                int row = wm * 128 + mf * 16 + kq * 4 + j;
                int col = wn * 64 + nf * 16 + lrow;
                Cbase[(size_t)row * N_DIM + col] = acc[mf][nf][j];
            }
        }
    }
}

// ---------------- Fallback: round-1 fused kernel ----------------
#define BM 128
#define BN 128
#define BK 64
#define KT (K_DIM / BK)

__device__ __forceinline__ int swz_f(int row, int kelem) {
    return kelem ^ (((row ^ (row >> 3)) & 7) << 3);
}

__global__ __launch_bounds__(256) void grouped_gemm_fused_kernel(
    const float* __restrict__ A, const float* __restrict__ W, float* __restrict__ C)
{
    const int bn = blockIdx.x;
    const int bm = blockIdx.y;
    const int e  = blockIdx.z;
    const int tid  = threadIdx.x;
    const int lane = tid & 63;
    const int wid  = tid >> 6;
    const int wr   = wid >> 1;
    const int wc   = wid & 1;

    __shared__ __align__(16) unsigned short fA[BM * BK];
    __shared__ __align__(16) unsigned short fB[BN * BK];

    const float* Abase = A + ((size_t)e * M_PER_E + (size_t)bm * BM) * K_DIM;
    const float* Wbase = W + (size_t)e * K_DIM * N_DIM + (size_t)bn * BN;
    float*       Cbase = C + ((size_t)e * M_PER_E + (size_t)bm * BM) * N_DIM + (size_t)bn * BN;

    const int arow  = tid >> 4;
    const int acol4 = (tid & 15) * 4;
    const int bkq   = tid >> 4;
    const int bnq   = tid & 15;

    f32x4 acc[4][4];
#pragma unroll
    for (int m = 0; m < 4; ++m)
#pragma unroll
        for (int n = 0; n < 4; ++n) acc[m][n] = (f32x4)0.0f;

    float4v ra[8], rb[8];

    auto LOADT = [&](int kt) {
        const float* ap = Abase + (size_t)arow * K_DIM + kt * BK + acol4;
#pragma unroll
        for (int i = 0; i < 8; ++i)
            ra[i] = *reinterpret_cast<const float4v*>(ap + (size_t)i * 16 * K_DIM);
        const float* bp = Wbase + (size_t)(kt * BK + bkq * 4) * N_DIM + bnq * 4;
#pragma unroll
        for (int i = 0; i < 2; ++i)
#pragma unroll
            for (int r = 0; r < 4; ++r)
                rb[i * 4 + r] = *reinterpret_cast<const float4v*>(bp + (size_t)r * N_DIM + i * 64);
    };

    auto STORET = [&]() {
#pragma unroll
        for (int i = 0; i < 8; ++i) {
            int row = arow + i * 16;
            ushort4v v = cvt4_bf16(ra[i]);
            *reinterpret_cast<ushort4v*>(&fA[row * BK + swz_f(row, acol4)]) = v;
        }
#pragma unroll
        for (int i = 0; i < 2; ++i) {
#pragma unroll
            for (int j = 0; j < 4; ++j) {
                int n = (bnq + i * 16) * 4 + j;
                float4v col;
                col[0] = rb[i * 4 + 0][j];
                col[1] = rb[i * 4 + 1][j];
                col[2] = rb[i * 4 + 2][j];
                col[3] = rb[i * 4 + 3][j];
                ushort4v v = cvt4_bf16(col);
                *reinterpret_cast<ushort4v*>(&fB[n * BK + swz_f(n, bkq * 4)]) = v;
            }
        }
    };

    auto COMPUTE = [&]() {
#pragma unroll
        for (int s = 0; s < 2; ++s) {
            bf16x8 af[4], bfr[4];
            const int ke = s * 32 + (lane >> 4) * 8;
#pragma unroll
            for (int m = 0; m < 4; ++m) {
                int row = wr * 64 + m * 16 + (lane & 15);
                af[m] = *reinterpret_cast<const bf16x8*>(&fA[row * BK + swz_f(row, ke)]);
            }
#pragma unroll
            for (int n = 0; n < 4; ++n) {
                int row = wc * 64 + n * 16 + (lane & 15);
                bfr[n] = *reinterpret_cast<const bf16x8*>(&fB[row * BK + swz_f(row, ke)]);
            }
#pragma unroll
            for (int m = 0; m < 4; ++m)
#pragma unroll
                for (int n = 0; n < 4; ++n)
                    acc[m][n] = __builtin_amdgcn_mfma_f32_16x16x32_bf16(
                        af[m], bfr[n], acc[m][n], 0, 0, 0);
        }
    };

    LOADT(0);
    STORET();
    __syncthreads();
    for (int kt = 0; kt < KT; ++kt) {
        if (kt + 1 < KT) LOADT(kt + 1);
        COMPUTE();
        __syncthreads();
        if (kt + 1 < KT) STORET();
        __syncthreads();
    }

#pragma unroll
    for (int m = 0; m < 4; ++m)
#pragma unroll
        for (int n = 0; n < 4; ++n)
#pragma unroll
            for (int j = 0; j < 4; ++j) {
                int row = wr * 64 + m * 16 + (lane >> 4) * 4 + j;
                int col = wc * 64 + n * 16 + (lane & 15);
                Cbase[(size_t)row * N_DIM + col] = acc[m][n][j];
            }
}

extern "C" void kernel_launch(void* const* d_in, const int* in_sizes, int n_in,
                              void* d_out, int out_size, void* d_ws, size_t ws_size,
                              hipStream_t stream) {
    const float* A = (const float*)d_in[0];
    // d_in[1] = expert_size (static 2048 each) — unused
    const float* W = (const float*)d_in[2];
    float* out = (float*)d_out;

    if (ws_size >= WS_NEEDED) {
        unsigned short* wsA = (unsigned short*)d_ws;
        unsigned short* wsW = wsA + (size_t)A_ELEMS;

        hipLaunchKernelGGL(convertA_kernel, dim3(2048), dim3(256), 0, stream,
                           A, wsA, A_ELEMS / 8);
        hipLaunchKernelGGL(transposeW_kernel, dim3(N_DIM / 64, K_DIM / 64, E_NUM),
                           dim3(256), 0, stream, W, wsW);
        hipLaunchKernelGGL(gemm_bf16_kernel, dim3(2048), dim3(512), 0, stream,
                           wsA, wsW, out);
    } else {
        dim3 grid(N_DIM / BN, M_PER_E / BM, E_NUM);
        hipLaunchKernelGGL(grouped_gemm_fused_kernel, grid, dim3(256), 0, stream,
                           A, W, out);
    }
}